// Round 15
// baseline (177.427 us; speedup 1.0000x reference)
//
#include <hip/hip_runtime.h>
#include <math.h>

#define B_ 256
#define M_ 3
#define L_ 100000
#define A_ 4096
#define H_ 512
#define MA_ (M_*A_)          // 12288 = K for GEMM1
#define K1_ MA_
#define NZ_ 32               // split-K chunks for GEMM1 (256 blocks -> 1/CU)
#define KC1_ (K1_/NZ_)       // 384
#define BCHUNK_ 4

#define NWIN_    98                    // label windows of 1024
#define NB_LGX_  98                    // l-chunk blocks per b-chunk
#define NB_LG_   (NB_LGX_*(B_/BCHUNK_))// 6272
#define NB_HW_   3072                  // H_*MA_/8/256
#define NB_W2_   1024                  // A_*H_/8/256
// Interleave: 128 groups x 81 blocks = 49 lg + 32 cvt each.
// 128*49 = 6272 = NB_LG_; 128*32 = 4096 = NB_HW_+NB_W2_.
#define GRP_     81
#define GLG_     49
#define NB_TOT_  (NB_LG_ + NB_HW_ + NB_W2_)

typedef __attribute__((ext_vector_type(8))) short bf16x8;
typedef __attribute__((ext_vector_type(8))) unsigned short u16x8;
typedef __attribute__((ext_vector_type(4))) float f32x4;
typedef __attribute__((ext_vector_type(4))) int i32x4;

static __device__ __forceinline__ f32x4 ld4(const float* p) {
    return *reinterpret_cast<const f32x4*>(p);
}
static __device__ __forceinline__ f32x4 ld4nt(const float* p) {
    return __builtin_nontemporal_load(reinterpret_cast<const f32x4*>(p));
}
static __device__ __forceinline__ void st4nt(float* p, f32x4 v) {
    __builtin_nontemporal_store(v, reinterpret_cast<f32x4*>(p));
}
static __device__ __forceinline__ unsigned short f2bf(float f) {
    unsigned u = __float_as_uint(f);
    unsigned r = (u + 0x7FFFu + ((u >> 16) & 1u)) >> 16;
    return (unsigned short)r;
}
static __device__ __forceinline__ float bf2f(unsigned short s) {
    return __uint_as_float((unsigned)s << 16);
}

// Consolidated pre-pass: block w inits head2 for its window, builds the
// label-sorted permutation slice, and emits the permuted bias b2p[j].
__global__ __launch_bounds__(256) void prepass(
    const int* __restrict__ idx, const float* __restrict__ b2,
    int* __restrict__ a_of_j, int* __restrict__ l_of_j,
    int* __restrict__ head2, float* __restrict__ b2p) {
    __shared__ int sidx[A_];
    __shared__ int ml[A_];
    __shared__ int ma[A_];
    __shared__ int nm_sh;
    __shared__ int base_sh;
    int w = blockIdx.x, tid = threadIdx.x;
    for (int i = tid; i < 1024; i += 256) {
        int l = (w << 10) + i;
        if (l < L_) head2[l] = -1;
    }
    for (int a = tid; a < A_; a += 256) sidx[a] = idx[a];
    if (tid == 0) { nm_sh = 0; base_sh = 0; }
    __syncthreads();
    int cnt_lt = 0;
    for (int a = tid; a < A_; a += 256) {
        int wa = sidx[a] >> 10;
        cnt_lt += (wa < w) ? 1 : 0;
        if (wa == w) { int p = atomicAdd(&nm_sh, 1); ml[p] = sidx[a]; ma[p] = a; }
    }
    atomicAdd(&base_sh, cnt_lt);
    __syncthreads();
    int nm = nm_sh, base = base_sh;
    for (int p = tid; p < nm; p += 256) {
        int l = ml[p], a = ma[p];
        int rank = 0, same_smaller = 0;
        for (int q = 0; q < nm; ++q) {
            int lq = ml[q], aq = ma[q];
            rank += (lq < l) | ((lq == l) & (aq < a));
            same_smaller += ((lq == l) & (aq < a));
        }
        int j = base + rank;
        a_of_j[j] = a;
        l_of_j[j] = l;
        b2p[j] = b2[a];
        if (same_smaller == 0) head2[l] = j;
    }
    if (w == 0 && tid == 0) l_of_j[A_] = -1;   // sentinel
}

// Mega-kernel: [logits+gather | hw cvt+col-permute | w2 cvt+ROW-permute],
// cvt blocks INTERLEAVED with lg blocks (32 per 81-group) so the streaming
// conversions fill lg's latency slack instead of serializing after it.
__global__ __launch_bounds__(256) void mega(
    const float* __restrict__ x, const float* __restrict__ gl,
    const float* __restrict__ dw, const float* __restrict__ bias,
    const int* __restrict__ head2, const int* __restrict__ l_of_j,
    const int* __restrict__ a_of_j,
    float* __restrict__ logits, unsigned short* __restrict__ xa,
    const float* __restrict__ hw, unsigned short* __restrict__ hwb,
    const float* __restrict__ w2, unsigned short* __restrict__ w2b) {
    int bid = blockIdx.x;
    int tid = threadIdx.x;
    int q = bid / GRP_, r = bid % GRP_;

    if (r >= GLG_) {
        int cvtbid = q * (GRP_ - GLG_) + (r - GLG_);
        if (cvtbid < NB_HW_) {
            int i = cvtbid * 256 + tid;
            int o = i * 8;
            int n = o / MA_;
            int col = o % MA_;
            int m = col >> 12, j0 = col & (A_ - 1);
            const float* row = hw + (size_t)n * MA_ + (m << 12);
            u16x8 out;
            #pragma unroll
            for (int t = 0; t < 8; ++t) out[t] = f2bf(row[a_of_j[j0 + t]]);
            *reinterpret_cast<u16x8*>(hwb + (size_t)o) = out;
        } else {
            // w2 fp32->bf16 with ROW permutation: w2b[j][k] = w2[a_of_j[j]][k]
            int i = (cvtbid - NB_HW_) * 256 + tid;
            int o = i * 8;
            int j = o >> 9;            // o / H_
            int k = o & (H_ - 1);      // o % H_
            const float* src = w2 + (size_t)a_of_j[j] * H_ + k;
            f32x4 v0 = ld4nt(src);
            f32x4 v1 = ld4nt(src + 4);
            u16x8 ov;
            ov[0] = f2bf(v0.x); ov[1] = f2bf(v0.y); ov[2] = f2bf(v0.z); ov[3] = f2bf(v0.w);
            ov[4] = f2bf(v1.x); ov[5] = f2bf(v1.y); ov[6] = f2bf(v1.z); ov[7] = f2bf(v1.w);
            *reinterpret_cast<u16x8*>(w2b + (size_t)o) = ov;
        }
        return;
    }

    int lgbid = q * GLG_ + r;
    const int L4 = L_ / 4;
    int i = (lgbid % NB_LGX_) * 256 + tid;
    if (i >= L4) return;
    int l = i * 4;
    int b0 = (lgbid / NB_LGX_) * BCHUNK_;

    float g0 = gl[0], g1 = gl[1], g2 = gl[2];
    float mx = fmaxf(g0, fmaxf(g1, g2));
    float e0 = expf(g0 - mx), e1 = expf(g1 - mx), e2 = expf(g2 - mx);
    float inv = 1.0f / (e0 + e1 + e2);
    float s0 = e0 * inv, s1 = e1 * inv, s2 = e2 * inv;

    f32x4 w0 = ld4(dw + l) + s0;
    f32x4 w1 = ld4(dw + L_ + l) + s1;
    f32x4 w2v = ld4(dw + 2 * L_ + l) + s2;
    f32x4 bb = ld4(bias + l);

    i32x4 heads = *reinterpret_cast<const i32x4*>(head2 + l);

    f32x4 X[BCHUNK_][3];
    #pragma unroll
    for (int c = 0; c < BCHUNK_; ++c) {
        const float* xb = x + (size_t)(b0 + c) * M_ * L_ + l;
        X[c][0] = ld4nt(xb);
        X[c][1] = ld4nt(xb + L_);
        X[c][2] = ld4nt(xb + 2 * L_);
    }
    #pragma unroll
    for (int c = 0; c < BCHUNK_; ++c) {
        f32x4 o = X[c][0] * w0 + X[c][1] * w1 + X[c][2] * w2v + bb;
        st4nt(logits + (size_t)(b0 + c) * L_ + l, o);
    }

    #pragma unroll
    for (int c = 0; c < 4; ++c) {
        int j = heads[c];
        if (j >= 0) {
            int lh = l + c;
            do {
                #pragma unroll
                for (int b = 0; b < BCHUNK_; ++b) {
                    unsigned short* xab = xa + (size_t)(b0 + b) * MA_;
                    xab[j]          = f2bf(X[b][0][c]);
                    xab[A_ + j]     = f2bf(X[b][1][c]);
                    xab[2 * A_ + j] = f2bf(X[b][2][c]);
                }
                ++j;
            } while (l_of_j[j] == lh);
        }
    }
}

// GEMM1 split-K MFMA, full-B row tile. Grid (z, colblk): XCD = z&7.
__global__ __launch_bounds__(256) void gemm1_mfma(
    const unsigned short* __restrict__ Xa, const unsigned short* __restrict__ W,
    unsigned short* __restrict__ part) {
    int tid = threadIdx.x;
    int wave = tid >> 6, lane = tid & 63;
    int row0 = wave * 64;
    int col0 = blockIdx.y * 64;
    int k0 = blockIdx.x * KC1_;
    int lr = lane & 15;
    int lk = (lane >> 4) * 8;
    const unsigned short* pa[4];
    const unsigned short* pb[4];
    #pragma unroll
    for (int i = 0; i < 4; ++i) {
        pa[i] = Xa + (size_t)(row0 + i * 16 + lr) * K1_ + k0 + lk;
        pb[i] = W + (size_t)(col0 + i * 16 + lr) * K1_ + k0 + lk;
    }
    f32x4 acc[4][4] = {};
    #pragma unroll 2
    for (int k = 0; k < KC1_; k += 32) {
        bf16x8 av[4], bv[4];
        #pragma unroll
        for (int i = 0; i < 4; ++i) av[i] = *reinterpret_cast<const bf16x8*>(pa[i] + k);
        #pragma unroll
        for (int i = 0; i < 4; ++i) bv[i] = *reinterpret_cast<const bf16x8*>(pb[i] + k);
        #pragma unroll
        for (int i = 0; i < 4; ++i)
            #pragma unroll
            for (int j = 0; j < 4; ++j)
                acc[i][j] = __builtin_amdgcn_mfma_f32_16x16x32_bf16(av[i], bv[j], acc[i][j], 0, 0, 0);
    }
    unsigned short* base = part + (size_t)blockIdx.x * B_ * H_;
    #pragma unroll
    for (int i = 0; i < 4; ++i) {
        #pragma unroll
        for (int j = 0; j < 4; ++j) {
            #pragma unroll
            for (int r = 0; r < 4; ++r) {
                int rr = (lane >> 4) * 4 + r;   // C/D: col=lane&15, row=(lane>>4)*4+r
                base[(size_t)(row0 + i * 16 + rr) * H_ + col0 + j * 16 + lr] = f2bf(acc[i][j][r]);
            }
        }
    }
}

// h[b,n] = bf16(relu(sum_z part[z,b,n] + hb[n])) -- u16x8 vectorized
__global__ void reduce_relu(const unsigned short* __restrict__ part,
                            const float* __restrict__ hb,
                            unsigned short* __restrict__ h) {
    int t = blockIdx.x * blockDim.x + threadIdx.x;
    if (t >= B_ * H_ / 8) return;
    int o = t * 8;
    float s[8];
    int n0 = o & (H_ - 1);
    #pragma unroll
    for (int e = 0; e < 8; ++e) s[e] = hb[n0 + e];
    #pragma unroll
    for (int z = 0; z < NZ_; ++z) {
        u16x8 v = *reinterpret_cast<const u16x8*>(part + (size_t)z * B_ * H_ + o);
        #pragma unroll
        for (int e = 0; e < 8; ++e) s[e] += bf2f(v[e]);
    }
    u16x8 ov;
    #pragma unroll
    for (int e = 0; e < 8; ++e) ov[e] = f2bf(fmaxf(s[e], 0.0f));
    *reinterpret_cast<u16x8*>(h + o) = ov;
}

// GEMM2 in j-space (W2 rows pre-permuted) + window-local atomic scatter.
__global__ __launch_bounds__(256) void gemm2_scatter(
    const unsigned short* __restrict__ Hm, const unsigned short* __restrict__ W2,
    const float* __restrict__ b2p, const float* __restrict__ la,
    const int* __restrict__ l_of_j, float* __restrict__ logits) {
    int tid = threadIdx.x;
    int wave = tid >> 6, lane = tid & 63;
    int row0 = blockIdx.x * 64 + (wave >> 1) * 32;
    int col0 = blockIdx.y * 64 + (wave & 1) * 32;
    int lr = lane & 15;
    int lk = (lane >> 4) * 8;
    const unsigned short* pa0 = Hm + (size_t)(row0 + lr) * H_ + lk;
    const unsigned short* pa1 = pa0 + (size_t)16 * H_;
    const unsigned short* pb0 = W2 + (size_t)(col0 + lr) * H_ + lk;
    const unsigned short* pb1 = pb0 + (size_t)16 * H_;
    f32x4 acc00 = {0.f,0.f,0.f,0.f}, acc01 = {0.f,0.f,0.f,0.f};
    f32x4 acc10 = {0.f,0.f,0.f,0.f}, acc11 = {0.f,0.f,0.f,0.f};
    #pragma unroll 4
    for (int k = 0; k < H_; k += 32) {
        bf16x8 a0 = *reinterpret_cast<const bf16x8*>(pa0 + k);
        bf16x8 a1 = *reinterpret_cast<const bf16x8*>(pa1 + k);
        bf16x8 b0 = *reinterpret_cast<const bf16x8*>(pb0 + k);
        bf16x8 b1 = *reinterpret_cast<const bf16x8*>(pb1 + k);
        acc00 = __builtin_amdgcn_mfma_f32_16x16x32_bf16(a0, b0, acc00, 0, 0, 0);
        acc01 = __builtin_amdgcn_mfma_f32_16x16x32_bf16(a0, b1, acc01, 0, 0, 0);
        acc10 = __builtin_amdgcn_mfma_f32_16x16x32_bf16(a1, b0, acc10, 0, 0, 0);
        acc11 = __builtin_amdgcn_mfma_f32_16x16x32_bf16(a1, b1, acc11, 0, 0, 0);
    }
    float alpha = 0.1f / (1.0f + expf(-la[0]));
    int c0 = col0 + lr, c1 = col0 + 16 + lr;
    int l0 = l_of_j[c0], l1 = l_of_j[c1];
    float bias0 = b2p[c0], bias1 = b2p[c1];
    #pragma unroll
    for (int j = 0; j < 4; ++j) {
        int r = (lane >> 4) * 4 + j;
        atomicAdd(&logits[(size_t)(row0 + r) * L_ + l0],      alpha * (acc00[j] + bias0));
        atomicAdd(&logits[(size_t)(row0 + r) * L_ + l1],      alpha * (acc01[j] + bias1));
        atomicAdd(&logits[(size_t)(row0 + 16 + r) * L_ + l0], alpha * (acc10[j] + bias0));
        atomicAdd(&logits[(size_t)(row0 + 16 + r) * L_ + l1], alpha * (acc11[j] + bias1));
    }
}

static inline size_t align256(size_t x) { return (x + 255) & ~(size_t)255; }

extern "C" void kernel_launch(void* const* d_in, const int* in_sizes, int n_in,
                              void* d_out, int out_size, void* d_ws, size_t ws_size,
                              hipStream_t stream) {
    const float* x    = (const float*)d_in[0];
    const int*   idx  = (const int*)d_in[1];
    const float* gl   = (const float*)d_in[2];
    const float* dw   = (const float*)d_in[3];
    const float* bias = (const float*)d_in[4];
    const float* la   = (const float*)d_in[5];
    const float* hw   = (const float*)d_in[6];
    const float* hb   = (const float*)d_in[7];
    const float* w2   = (const float*)d_in[8];
    const float* b2   = (const float*)d_in[9];
    float* logits = (float*)d_out;

    char* ws = (char*)d_ws;
    int* head2 = (int*)ws;                     ws += align256((size_t)L_ * 4);
    int* a_of_j = (int*)ws;                    ws += align256((size_t)A_ * 4);
    int* l_of_j = (int*)ws;                    ws += align256((size_t)(A_ + 1) * 4);
    float* b2p = (float*)ws;                   ws += align256((size_t)A_ * 4);
    unsigned short* xa = (unsigned short*)ws;  ws += align256((size_t)B_ * MA_ * 2);
    unsigned short* hwb = (unsigned short*)ws; ws += align256((size_t)H_ * MA_ * 2);
    unsigned short* w2b = (unsigned short*)ws; ws += align256((size_t)A_ * H_ * 2);
    unsigned short* part = (unsigned short*)ws; ws += align256((size_t)NZ_ * B_ * H_ * 2);
    unsigned short* h = (unsigned short*)ws;   ws += align256((size_t)B_ * H_ * 2);

    prepass<<<NWIN_, 256, 0, stream>>>(idx, b2, a_of_j, l_of_j, head2, b2p);

    mega<<<NB_TOT_, 256, 0, stream>>>(
        x, gl, dw, bias, head2, l_of_j, a_of_j, logits, xa, hw, hwb, w2, w2b);

    gemm1_mfma<<<dim3(NZ_, H_ / 64), 256, 0, stream>>>(xa, hwb, part);
    reduce_relu<<<(B_ * H_ / 8 + 255) / 256, 256, 0, stream>>>(part, hb, h);
    gemm2_scatter<<<dim3(B_ / 64, A_ / 64), 256, 0, stream>>>(h, w2b, b2p, la, l_of_j, logits);
}

// Round 16
// 172.684 us; speedup vs baseline: 1.0275x; 1.0275x over previous
//
#include <hip/hip_runtime.h>
#include <math.h>

#define B_ 256
#define M_ 3
#define L_ 100000
#define A_ 4096
#define H_ 512
#define MA_ (M_*A_)          // 12288 = K for GEMM1
#define K1_ MA_
#define NZ_ 32               // split-K chunks for GEMM1 (256 blocks -> 1/CU)
#define KC1_ (K1_/NZ_)       // 384
#define BCHUNK_ 4

#define NWIN_    98                    // label windows of 1024
#define NB_LGX_  98                    // l-chunk blocks per b-chunk
#define NB_LG_   (NB_LGX_*(B_/BCHUNK_))// 6272
#define NB_HW_   3072                  // H_*MA_/8/256
#define NB_W2_   1024                  // A_*H_/8/256

typedef __attribute__((ext_vector_type(8))) short bf16x8;
typedef __attribute__((ext_vector_type(8))) unsigned short u16x8;
typedef __attribute__((ext_vector_type(4))) float f32x4;
typedef __attribute__((ext_vector_type(4))) int i32x4;

static __device__ __forceinline__ f32x4 ld4(const float* p) {
    return *reinterpret_cast<const f32x4*>(p);
}
static __device__ __forceinline__ f32x4 ld4nt(const float* p) {
    return __builtin_nontemporal_load(reinterpret_cast<const f32x4*>(p));
}
static __device__ __forceinline__ void st4nt(float* p, f32x4 v) {
    __builtin_nontemporal_store(v, reinterpret_cast<f32x4*>(p));
}
static __device__ __forceinline__ unsigned short f2bf(float f) {
    unsigned u = __float_as_uint(f);
    unsigned r = (u + 0x7FFFu + ((u >> 16) & 1u)) >> 16;
    return (unsigned short)r;
}
static __device__ __forceinline__ float bf2f(unsigned short s) {
    return __uint_as_float((unsigned)s << 16);
}

// Consolidated pre-pass: block w inits head2 for its window, builds the
// label-sorted permutation slice, and emits the permuted bias b2p[j].
__global__ __launch_bounds__(256) void prepass(
    const int* __restrict__ idx, const float* __restrict__ b2,
    int* __restrict__ a_of_j, int* __restrict__ l_of_j,
    int* __restrict__ head2, float* __restrict__ b2p) {
    __shared__ int sidx[A_];
    __shared__ int ml[A_];
    __shared__ int ma[A_];
    __shared__ int nm_sh;
    __shared__ int base_sh;
    int w = blockIdx.x, tid = threadIdx.x;
    for (int i = tid; i < 1024; i += 256) {
        int l = (w << 10) + i;
        if (l < L_) head2[l] = -1;
    }
    for (int a = tid; a < A_; a += 256) sidx[a] = idx[a];
    if (tid == 0) { nm_sh = 0; base_sh = 0; }
    __syncthreads();
    int cnt_lt = 0;
    for (int a = tid; a < A_; a += 256) {
        int wa = sidx[a] >> 10;
        cnt_lt += (wa < w) ? 1 : 0;
        if (wa == w) { int p = atomicAdd(&nm_sh, 1); ml[p] = sidx[a]; ma[p] = a; }
    }
    atomicAdd(&base_sh, cnt_lt);
    __syncthreads();
    int nm = nm_sh, base = base_sh;
    for (int p = tid; p < nm; p += 256) {
        int l = ml[p], a = ma[p];
        int rank = 0, same_smaller = 0;
        for (int q = 0; q < nm; ++q) {
            int lq = ml[q], aq = ma[q];
            rank += (lq < l) | ((lq == l) & (aq < a));
            same_smaller += ((lq == l) & (aq < a));
        }
        int j = base + rank;
        a_of_j[j] = a;
        l_of_j[j] = l;
        b2p[j] = b2[a];
        if (same_smaller == 0) head2[l] = j;
    }
    if (w == 0 && tid == 0) l_of_j[A_] = -1;   // sentinel
}

// Mega-kernel (R14 champion): [logits+gather | hw cvt+col-permute | w2 cvt+ROW-permute]
__global__ __launch_bounds__(256) void mega(
    const float* __restrict__ x, const float* __restrict__ gl,
    const float* __restrict__ dw, const float* __restrict__ bias,
    const int* __restrict__ head2, const int* __restrict__ l_of_j,
    const int* __restrict__ a_of_j,
    float* __restrict__ logits, unsigned short* __restrict__ xa,
    const float* __restrict__ hw, unsigned short* __restrict__ hwb,
    const float* __restrict__ w2, unsigned short* __restrict__ w2b) {
    int bid = blockIdx.x;
    int tid = threadIdx.x;

    if (bid >= NB_LG_) {
        if (bid < NB_LG_ + NB_HW_) {
            int i = (bid - NB_LG_) * 256 + tid;
            int o = i * 8;
            int n = o / MA_;
            int col = o % MA_;
            int m = col >> 12, j0 = col & (A_ - 1);
            const float* row = hw + (size_t)n * MA_ + (m << 12);
            u16x8 out;
            #pragma unroll
            for (int t = 0; t < 8; ++t) out[t] = f2bf(row[a_of_j[j0 + t]]);
            *reinterpret_cast<u16x8*>(hwb + (size_t)o) = out;
        } else {
            // w2 fp32->bf16 with ROW permutation: w2b[j][k] = w2[a_of_j[j]][k]
            int i = (bid - NB_LG_ - NB_HW_) * 256 + tid;
            int o = i * 8;
            int j = o >> 9;            // o / H_
            int k = o & (H_ - 1);      // o % H_
            const float* src = w2 + (size_t)a_of_j[j] * H_ + k;
            f32x4 v0 = ld4nt(src);
            f32x4 v1 = ld4nt(src + 4);
            u16x8 ov;
            ov[0] = f2bf(v0.x); ov[1] = f2bf(v0.y); ov[2] = f2bf(v0.z); ov[3] = f2bf(v0.w);
            ov[4] = f2bf(v1.x); ov[5] = f2bf(v1.y); ov[6] = f2bf(v1.z); ov[7] = f2bf(v1.w);
            *reinterpret_cast<u16x8*>(w2b + (size_t)o) = ov;
        }
        return;
    }

    const int L4 = L_ / 4;
    int i = (bid % NB_LGX_) * 256 + tid;
    if (i >= L4) return;
    int l = i * 4;
    int b0 = (bid / NB_LGX_) * BCHUNK_;

    float g0 = gl[0], g1 = gl[1], g2 = gl[2];
    float mx = fmaxf(g0, fmaxf(g1, g2));
    float e0 = expf(g0 - mx), e1 = expf(g1 - mx), e2 = expf(g2 - mx);
    float inv = 1.0f / (e0 + e1 + e2);
    float s0 = e0 * inv, s1 = e1 * inv, s2 = e2 * inv;

    f32x4 w0 = ld4(dw + l) + s0;
    f32x4 w1 = ld4(dw + L_ + l) + s1;
    f32x4 w2v = ld4(dw + 2 * L_ + l) + s2;
    f32x4 bb = ld4(bias + l);

    i32x4 heads = *reinterpret_cast<const i32x4*>(head2 + l);

    f32x4 X[BCHUNK_][3];
    #pragma unroll
    for (int c = 0; c < BCHUNK_; ++c) {
        const float* xb = x + (size_t)(b0 + c) * M_ * L_ + l;
        X[c][0] = ld4nt(xb);
        X[c][1] = ld4nt(xb + L_);
        X[c][2] = ld4nt(xb + 2 * L_);
    }
    #pragma unroll
    for (int c = 0; c < BCHUNK_; ++c) {
        f32x4 o = X[c][0] * w0 + X[c][1] * w1 + X[c][2] * w2v + bb;
        st4nt(logits + (size_t)(b0 + c) * L_ + l, o);
    }

    #pragma unroll
    for (int c = 0; c < 4; ++c) {
        int j = heads[c];
        if (j >= 0) {
            int lh = l + c;
            do {
                #pragma unroll
                for (int b = 0; b < BCHUNK_; ++b) {
                    unsigned short* xab = xa + (size_t)(b0 + b) * MA_;
                    xab[j]          = f2bf(X[b][0][c]);
                    xab[A_ + j]     = f2bf(X[b][1][c]);
                    xab[2 * A_ + j] = f2bf(X[b][2][c]);
                }
                ++j;
            } while (l_of_j[j] == lh);
        }
    }
}

// GEMM1 split-K MFMA, full-B row tile. Grid (z, colblk): XCD = z&7.
__global__ __launch_bounds__(256) void gemm1_mfma(
    const unsigned short* __restrict__ Xa, const unsigned short* __restrict__ W,
    unsigned short* __restrict__ part) {
    int tid = threadIdx.x;
    int wave = tid >> 6, lane = tid & 63;
    int row0 = wave * 64;
    int col0 = blockIdx.y * 64;
    int k0 = blockIdx.x * KC1_;
    int lr = lane & 15;
    int lk = (lane >> 4) * 8;
    const unsigned short* pa[4];
    const unsigned short* pb[4];
    #pragma unroll
    for (int i = 0; i < 4; ++i) {
        pa[i] = Xa + (size_t)(row0 + i * 16 + lr) * K1_ + k0 + lk;
        pb[i] = W + (size_t)(col0 + i * 16 + lr) * K1_ + k0 + lk;
    }
    f32x4 acc[4][4] = {};
    #pragma unroll 2
    for (int k = 0; k < KC1_; k += 32) {
        bf16x8 av[4], bv[4];
        #pragma unroll
        for (int i = 0; i < 4; ++i) av[i] = *reinterpret_cast<const bf16x8*>(pa[i] + k);
        #pragma unroll
        for (int i = 0; i < 4; ++i) bv[i] = *reinterpret_cast<const bf16x8*>(pb[i] + k);
        #pragma unroll
        for (int i = 0; i < 4; ++i)
            #pragma unroll
            for (int j = 0; j < 4; ++j)
                acc[i][j] = __builtin_amdgcn_mfma_f32_16x16x32_bf16(av[i], bv[j], acc[i][j], 0, 0, 0);
    }
    unsigned short* base = part + (size_t)blockIdx.x * B_ * H_;
    #pragma unroll
    for (int i = 0; i < 4; ++i) {
        #pragma unroll
        for (int j = 0; j < 4; ++j) {
            #pragma unroll
            for (int r = 0; r < 4; ++r) {
                int rr = (lane >> 4) * 4 + r;   // C/D: col=lane&15, row=(lane>>4)*4+r
                base[(size_t)(row0 + i * 16 + rr) * H_ + col0 + j * 16 + lr] = f2bf(acc[i][j][r]);
            }
        }
    }
}

// h[b,n] = bf16(relu(sum_z part[z,b,n] + hb[n])) -- u16x8 vectorized
__global__ void reduce_relu(const unsigned short* __restrict__ part,
                            const float* __restrict__ hb,
                            unsigned short* __restrict__ h) {
    int t = blockIdx.x * blockDim.x + threadIdx.x;
    if (t >= B_ * H_ / 8) return;
    int o = t * 8;
    float s[8];
    int n0 = o & (H_ - 1);
    #pragma unroll
    for (int e = 0; e < 8; ++e) s[e] = hb[n0 + e];
    #pragma unroll
    for (int z = 0; z < NZ_; ++z) {
        u16x8 v = *reinterpret_cast<const u16x8*>(part + (size_t)z * B_ * H_ + o);
        #pragma unroll
        for (int e = 0; e < 8; ++e) s[e] += bf2f(v[e]);
    }
    u16x8 ov;
    #pragma unroll
    for (int e = 0; e < 8; ++e) ov[e] = f2bf(fmaxf(s[e], 0.0f));
    *reinterpret_cast<u16x8*>(h + o) = ov;
}

// GEMM2 in j-space + window-local atomic scatter. Grid (colblk, rowblk):
// bid = col + 64*row -> XCD = col&7 for all 4 row-blocks of a column, so
// each W2 column-slice is fetched once per XCD instead of 4x.
__global__ __launch_bounds__(256) void gemm2_scatter(
    const unsigned short* __restrict__ Hm, const unsigned short* __restrict__ W2,
    const float* __restrict__ b2p, const float* __restrict__ la,
    const int* __restrict__ l_of_j, float* __restrict__ logits) {
    int tid = threadIdx.x;
    int wave = tid >> 6, lane = tid & 63;
    int row0 = blockIdx.y * 64 + (wave >> 1) * 32;
    int col0 = blockIdx.x * 64 + (wave & 1) * 32;
    int lr = lane & 15;
    int lk = (lane >> 4) * 8;
    const unsigned short* pa0 = Hm + (size_t)(row0 + lr) * H_ + lk;
    const unsigned short* pa1 = pa0 + (size_t)16 * H_;
    const unsigned short* pb0 = W2 + (size_t)(col0 + lr) * H_ + lk;
    const unsigned short* pb1 = pb0 + (size_t)16 * H_;
    f32x4 acc00 = {0.f,0.f,0.f,0.f}, acc01 = {0.f,0.f,0.f,0.f};
    f32x4 acc10 = {0.f,0.f,0.f,0.f}, acc11 = {0.f,0.f,0.f,0.f};
    #pragma unroll 4
    for (int k = 0; k < H_; k += 32) {
        bf16x8 a0 = *reinterpret_cast<const bf16x8*>(pa0 + k);
        bf16x8 a1 = *reinterpret_cast<const bf16x8*>(pa1 + k);
        bf16x8 b0 = *reinterpret_cast<const bf16x8*>(pb0 + k);
        bf16x8 b1 = *reinterpret_cast<const bf16x8*>(pb1 + k);
        acc00 = __builtin_amdgcn_mfma_f32_16x16x32_bf16(a0, b0, acc00, 0, 0, 0);
        acc01 = __builtin_amdgcn_mfma_f32_16x16x32_bf16(a0, b1, acc01, 0, 0, 0);
        acc10 = __builtin_amdgcn_mfma_f32_16x16x32_bf16(a1, b0, acc10, 0, 0, 0);
        acc11 = __builtin_amdgcn_mfma_f32_16x16x32_bf16(a1, b1, acc11, 0, 0, 0);
    }
    float alpha = 0.1f / (1.0f + expf(-la[0]));
    int c0 = col0 + lr, c1 = col0 + 16 + lr;
    int l0 = l_of_j[c0], l1 = l_of_j[c1];
    float bias0 = b2p[c0], bias1 = b2p[c1];
    #pragma unroll
    for (int j = 0; j < 4; ++j) {
        int r = (lane >> 4) * 4 + j;
        atomicAdd(&logits[(size_t)(row0 + r) * L_ + l0],      alpha * (acc00[j] + bias0));
        atomicAdd(&logits[(size_t)(row0 + r) * L_ + l1],      alpha * (acc01[j] + bias1));
        atomicAdd(&logits[(size_t)(row0 + 16 + r) * L_ + l0], alpha * (acc10[j] + bias0));
        atomicAdd(&logits[(size_t)(row0 + 16 + r) * L_ + l1], alpha * (acc11[j] + bias1));
    }
}

static inline size_t align256(size_t x) { return (x + 255) & ~(size_t)255; }

extern "C" void kernel_launch(void* const* d_in, const int* in_sizes, int n_in,
                              void* d_out, int out_size, void* d_ws, size_t ws_size,
                              hipStream_t stream) {
    const float* x    = (const float*)d_in[0];
    const int*   idx  = (const int*)d_in[1];
    const float* gl   = (const float*)d_in[2];
    const float* dw   = (const float*)d_in[3];
    const float* bias = (const float*)d_in[4];
    const float* la   = (const float*)d_in[5];
    const float* hw   = (const float*)d_in[6];
    const float* hb   = (const float*)d_in[7];
    const float* w2   = (const float*)d_in[8];
    const float* b2   = (const float*)d_in[9];
    float* logits = (float*)d_out;

    char* ws = (char*)d_ws;
    int* head2 = (int*)ws;                     ws += align256((size_t)L_ * 4);
    int* a_of_j = (int*)ws;                    ws += align256((size_t)A_ * 4);
    int* l_of_j = (int*)ws;                    ws += align256((size_t)(A_ + 1) * 4);
    float* b2p = (float*)ws;                   ws += align256((size_t)A_ * 4);
    unsigned short* xa = (unsigned short*)ws;  ws += align256((size_t)B_ * MA_ * 2);
    unsigned short* hwb = (unsigned short*)ws; ws += align256((size_t)H_ * MA_ * 2);
    unsigned short* w2b = (unsigned short*)ws; ws += align256((size_t)A_ * H_ * 2);
    unsigned short* part = (unsigned short*)ws; ws += align256((size_t)NZ_ * B_ * H_ * 2);
    unsigned short* h = (unsigned short*)ws;   ws += align256((size_t)B_ * H_ * 2);

    prepass<<<NWIN_, 256, 0, stream>>>(idx, b2, a_of_j, l_of_j, head2, b2p);

    mega<<<NB_LG_ + NB_HW_ + NB_W2_, 256, 0, stream>>>(
        x, gl, dw, bias, head2, l_of_j, a_of_j, logits, xa, hw, hwb, w2, w2b);

    gemm1_mfma<<<dim3(NZ_, H_ / 64), 256, 0, stream>>>(xa, hwb, part);
    reduce_relu<<<(B_ * H_ / 8 + 255) / 256, 256, 0, stream>>>(part, hb, h);
    gemm2_scatter<<<dim3(A_ / 64, B_ / 64), 256, 0, stream>>>(h, w2b, b2p, la, l_of_j, logits);
}